// Round 11
// baseline (766.435 us; speedup 1.0000x reference)
//
#include <hip/hip_runtime.h>

#define NNODES 100000
#define NEDGES 1600000
#define NGRAPHS 128
#define HID 128
#define NBKT 782            // ceil(100000/128)
#define NPAD  (NBKT * 128)  // 100096
#define CHUNK 8192
#define NCHB ((NEDGES + CHUNK - 1) / CHUNK)   // 196
#define MAXB 3072           // bucket edge cap (mean 2048, sigma ~45)
#define NSL 8               // feature slices (16 feats = 32 B each)
#define SLS (NPAD * 16)     // slice stride in ushorts (3.2 MB)

typedef unsigned short ushort_t;
typedef unsigned int uint_t;
typedef unsigned long long u64;
typedef __attribute__((ext_vector_type(8))) short short8;
typedef __attribute__((ext_vector_type(4))) float floatx4;
typedef __attribute__((ext_vector_type(4))) unsigned int uint4e;

__device__ __forceinline__ float bf2f(ushort_t u) {
    return __uint_as_float(((unsigned)u) << 16);
}
__device__ __forceinline__ ushort_t f2bf(float f) {
    unsigned u = __float_as_uint(f);
    return (ushort_t)((u + 0x7fffu + ((u >> 16) & 1u)) >> 16);
}

// ---------------- bucket histogram (LDS-staged) ----------------
__global__ void hist_k(const int* __restrict__ col, int* __restrict__ bcnt) {
    __shared__ int l[NBKT];
    for (int i = threadIdx.x; i < NBKT; i += 256) l[i] = 0;
    __syncthreads();
    int base = blockIdx.x * CHUNK;
    int lim = base + CHUNK < NEDGES ? base + CHUNK : NEDGES;
    for (int e = base + threadIdx.x; e < lim; e += 256)
        atomicAdd(&l[col[e] >> 7], 1);
    __syncthreads();
    for (int i = threadIdx.x; i < NBKT; i += 256)
        if (l[i]) atomicAdd(&bcnt[i], l[i]);
}

// ---------------- scan 782 buckets (single block) ----------------
__global__ void bscan_k(const int* __restrict__ bcnt, int* __restrict__ bbase,
                        int* __restrict__ gc) {
    __shared__ int l[1024];
    int t = threadIdx.x;
    int v0 = (t < NBKT) ? bcnt[t] : 0;
    l[t] = v0;
    __syncthreads();
    for (int d = 1; d < 1024; d <<= 1) {
        int v = (t >= d) ? l[t - d] : 0;
        __syncthreads();
        l[t] += v;
        __syncthreads();
    }
    if (t < NBKT) { int ex = l[t] - v0; bbase[t] = ex; gc[t] = ex; }
    if (t == 0) bbase[NBKT] = NEDGES;
}

// ---------------- bucket scatter: one range-claim atomic per (block,bucket) ----------------
__global__ void bfill_k(const int* __restrict__ row, const int* __restrict__ col,
                        int* __restrict__ gc, uint_t* __restrict__ entry) {
    __shared__ int lcnt[NBKT], lbase[NBKT];
    for (int i = threadIdx.x; i < NBKT; i += 256) lcnt[i] = 0;
    __syncthreads();
    int base = blockIdx.x * CHUNK;
    int lim = base + CHUNK < NEDGES ? base + CHUNK : NEDGES;
    for (int e = base + threadIdx.x; e < lim; e += 256)
        atomicAdd(&lcnt[col[e] >> 7], 1);
    __syncthreads();
    for (int i = threadIdx.x; i < NBKT; i += 256) {
        int c = lcnt[i];
        lbase[i] = c ? atomicAdd(&gc[i], c) : 0;
        lcnt[i] = 0;   // reuse as fill cursor
    }
    __syncthreads();
    for (int e = base + threadIdx.x; e < lim; e += 256) {
        int c = col[e];
        int b = c >> 7;
        int pos = lbase[b] + atomicAdd(&lcnt[b], 1);
        entry[pos] = (uint_t)row[e] | ((uint_t)(c & 127) << 17);
    }
}

// ---------------- per-bucket LDS counting sort -> csr_src, degi, off ----------------
__global__ void sortb_k(const uint_t* __restrict__ entry, const int* __restrict__ bbase,
                        int* __restrict__ csr_src, int* __restrict__ degi,
                        int* __restrict__ off) {
    __shared__ uint_t ents[MAXB];
    __shared__ uint_t sorted[MAXB];
    __shared__ int ncnt[128], nsc[128], nfill[128];
    int b = blockIdx.x;
    int base = bbase[b];
    int cnt = bbase[b + 1] - base;
    if (cnt > MAXB) cnt = MAXB;
    int t = threadIdx.x;
    if (t < 128) { ncnt[t] = 0; nfill[t] = 0; }
    __syncthreads();
    for (int i = t; i < cnt; i += 256) {
        uint_t v = entry[base + i];
        ents[i] = v;
        atomicAdd(&ncnt[v >> 17], 1);
    }
    __syncthreads();
    if (t < 128) nsc[t] = ncnt[t];
    __syncthreads();
    for (int d = 1; d < 128; d <<= 1) {
        int v = (t >= d && t < 128) ? nsc[t - d] : 0;
        __syncthreads();
        if (t < 128) nsc[t] += v;   // inclusive scan
        __syncthreads();
    }
    if (t < 128) {
        int n = b * 128 + t;
        if (n < NNODES) { degi[n] = ncnt[t]; off[n] = base + nsc[t]; }
        nsc[t] -= ncnt[t];          // exclusive
    }
    __syncthreads();
    for (int i = t; i < cnt; i += 256) {
        uint_t v = ents[i];
        int dl = v >> 17;
        int pos = nsc[dl] + atomicAdd(&nfill[dl], 1);
        sorted[pos] = v & 0x1FFFFu;
    }
    __syncthreads();
    for (int i = t; i < cnt; i += 256) csr_src[base + i] = (int)sorted[i];
}

// ---------------- fused: dinv + Wt transpose + graph bounds ----------------
__global__ void misc_k(const int* __restrict__ degi, float* __restrict__ dinv,
                       const float* __restrict__ W2, ushort_t* __restrict__ Wt,
                       const int* __restrict__ batch,
                       int* __restrict__ first, int* __restrict__ last) {
    int i = blockIdx.x * 256 + threadIdx.x;
    if (i < NNODES) {
        int d = degi[i];
        dinv[i] = (d > 0) ? rsqrtf((float)d) : 0.0f;
        int g = batch[i];
        if (i == 0 || batch[i - 1] != g) first[g] = i;
        if (i == NNODES - 1 || batch[i + 1] != g) last[g] = i;
    }
    if (i < 512 * 128) {
        int j = i >> 9, k = i & 511;
        Wt[i] = f2bf(W2[k * 128 + j]);   // Wt[j][k], k = hop*128+i
    }
}

// ---------------- packed edges: epk[k] = {src, w = dinv[src]*dinv[dst]} ----------------
__global__ void wfill_k(const int* __restrict__ off, const int* __restrict__ csr_src,
                        const float* __restrict__ dinv, uint2* __restrict__ epk) {
    int n = blockIdx.x * 256 + threadIdx.x;
    if (n >= NNODES) return;
    int k = n ? off[n - 1] : 0;
    int end = off[n];
    float dn = dinv[n];
    for (; k < end; k++) {
        int s = csr_src[k];
        epk[k] = make_uint2((uint_t)s, __float_as_uint(dinv[s] * dn));
    }
}

// ---------------- layer-1 gather (F=4, fp32), packed edges, unroll 4 ----------------
__global__ void gprop4(const int* __restrict__ off, const uint2* __restrict__ epk,
                       const float* __restrict__ hin, float* __restrict__ hout) {
    int n = blockIdx.x * 256 + threadIdx.x;
    if (n >= NNODES) return;
    int k = n ? off[n - 1] : 0;
    int end = off[n];
    float4 acc = {0.f, 0.f, 0.f, 0.f};
    for (; k + 3 < end; k += 4) {
        uint2 e0 = epk[k], e1 = epk[k + 1], e2 = epk[k + 2], e3 = epk[k + 3];
        float w0 = __uint_as_float(e0.y), w1 = __uint_as_float(e1.y);
        float w2 = __uint_as_float(e2.y), w3 = __uint_as_float(e3.y);
        float4 v0 = *(const float4*)(hin + e0.x * 4);
        float4 v1 = *(const float4*)(hin + e1.x * 4);
        float4 v2 = *(const float4*)(hin + e2.x * 4);
        float4 v3 = *(const float4*)(hin + e3.x * 4);
        acc.x += w0 * v0.x + w1 * v1.x + w2 * v2.x + w3 * v3.x;
        acc.y += w0 * v0.y + w1 * v1.y + w2 * v2.y + w3 * v3.y;
        acc.z += w0 * v0.z + w1 * v1.z + w2 * v2.z + w3 * v3.z;
        acc.w += w0 * v0.w + w1 * v1.w + w2 * v2.w + w3 * v3.w;
    }
    for (; k < end; k++) {
        uint2 e = epk[k];
        float w = __uint_as_float(e.y);
        float4 v = *(const float4*)(hin + e.x * 4);
        acc.x += w * v.x; acc.y += w * v.y; acc.z += w * v.z; acc.w += w * v.w;
    }
    *(float4*)(hout + n * 4) = acc;
}

// ---------------- layer-2 gather helper: acc8 += wgt * bf16x8(v) ----------------
__device__ __forceinline__ void acc8(float* a, float wgt, uint4 v) {
    a[0] += wgt * __uint_as_float(v.x << 16);
    a[1] += wgt * __uint_as_float(v.x & 0xffff0000u);
    a[2] += wgt * __uint_as_float(v.y << 16);
    a[3] += wgt * __uint_as_float(v.y & 0xffff0000u);
    a[4] += wgt * __uint_as_float(v.z << 16);
    a[5] += wgt * __uint_as_float(v.z & 0xffff0000u);
    a[6] += wgt * __uint_as_float(v.w << 16);
    a[7] += wgt * __uint_as_float(v.w & 0xffff0000u);
}

// ---------------- layer-2 gather, XCD-pinned feature slices ----------------
// P layout: [slice=8][NPAD][16] bf16 (3.2 MB/slice, fits 4 MiB per-XCD L2).
// slice = blockIdx.x & 7 -> block lands on XCD (blockIdx % 8): each XCD gathers
// only from its resident slice. epk loads + output stores are nontemporal
// (no intra-XCD reuse) so they don't evict the slice.
__global__ void gprop128s(const int* __restrict__ off, const uint2* __restrict__ epk,
                          const ushort_t* __restrict__ Pin, ushort_t* __restrict__ Pout) {
    int s = blockIdx.x & 7;
    int nb = blockIdx.x >> 3;
    int n = nb * 128 + (threadIdx.x >> 1);
    if (n >= NNODES) return;
    int lane = threadIdx.x & 1;
    int k = n ? off[n - 1] : 0;
    int end = off[n];
    const ushort_t* Ps_ = Pin + (size_t)s * SLS;
    int fo = lane * 8;
    float a[8] = {0.f, 0.f, 0.f, 0.f, 0.f, 0.f, 0.f, 0.f};
    const u64* ep = (const u64*)epk;
    for (; k + 3 < end; k += 4) {
        u64 e0 = __builtin_nontemporal_load(ep + k);
        u64 e1 = __builtin_nontemporal_load(ep + k + 1);
        u64 e2 = __builtin_nontemporal_load(ep + k + 2);
        u64 e3 = __builtin_nontemporal_load(ep + k + 3);
        uint4 v0 = *(const uint4*)(Ps_ + (uint_t)(e0 & 0xffffffffu) * 16 + fo);
        uint4 v1 = *(const uint4*)(Ps_ + (uint_t)(e1 & 0xffffffffu) * 16 + fo);
        uint4 v2 = *(const uint4*)(Ps_ + (uint_t)(e2 & 0xffffffffu) * 16 + fo);
        uint4 v3 = *(const uint4*)(Ps_ + (uint_t)(e3 & 0xffffffffu) * 16 + fo);
        acc8(a, __uint_as_float((uint_t)(e0 >> 32)), v0);
        acc8(a, __uint_as_float((uint_t)(e1 >> 32)), v1);
        acc8(a, __uint_as_float((uint_t)(e2 >> 32)), v2);
        acc8(a, __uint_as_float((uint_t)(e3 >> 32)), v3);
    }
    for (; k < end; k++) {
        u64 e = __builtin_nontemporal_load(ep + k);
        uint4 v = *(const uint4*)(Ps_ + (uint_t)(e & 0xffffffffu) * 16 + fo);
        acc8(a, __uint_as_float((uint_t)(e >> 32)), v);
    }
    uint4e o;
    o.x = (unsigned)f2bf(a[0]) | ((unsigned)f2bf(a[1]) << 16);
    o.y = (unsigned)f2bf(a[2]) | ((unsigned)f2bf(a[3]) << 16);
    o.z = (unsigned)f2bf(a[4]) | ((unsigned)f2bf(a[5]) << 16);
    o.w = (unsigned)f2bf(a[6]) | ((unsigned)f2bf(a[7]) << 16);
    __builtin_nontemporal_store(o, (uint4e*)(Pout + (size_t)s * SLS + (size_t)n * 16 + fo));
}

// ---------------- layer-1 combine -> bf16 P0 (sliced layout) ----------------
__global__ void combine1(const float* __restrict__ x, const float* __restrict__ h1,
                         const float* __restrict__ h2, const float* __restrict__ h3,
                         const float* __restrict__ W1, const float* __restrict__ b1,
                         ushort_t* __restrict__ P0) {
    __shared__ float hs[4][16];
    int n0 = blockIdx.x * 4;
    int j = threadIdx.x;  // 0..127
    if (j < 64) {
        int n = j >> 4, v = j & 15, k = v >> 2, i = v & 3;
        const float* src = (k == 0) ? x : (k == 1) ? h1 : (k == 2) ? h2 : h3;
        hs[n][v] = src[(n0 + n) * 4 + i];
    }
    __syncthreads();
    float w[16];
#pragma unroll
    for (int v = 0; v < 16; v++) w[v] = W1[v * 128 + j];
    float bb = b1[j];
    int sbase = (j >> 4) * SLS + (j & 15);
#pragma unroll
    for (int n = 0; n < 4; n++) {
        float acc = bb;
#pragma unroll
        for (int v = 0; v < 16; v++) acc += hs[n][v] * w[v];
        P0[sbase + (n0 + n) * 16] = f2bf(fmaxf(acc, 0.0f));
    }
}

// ---------------- fused MFMA + pool, B staged in LDS, A from sliced P ----------------
__global__ __launch_bounds__(256) void gemm4p(
    const ushort_t* __restrict__ P0, const ushort_t* __restrict__ P1,
    const ushort_t* __restrict__ P2, const ushort_t* __restrict__ P3,
    const ushort_t* __restrict__ Wt, const float* __restrict__ b2,
    const int* __restrict__ batch, float* __restrict__ sums) {
    __shared__ ushort_t Bs[32768];   // 64 KB: 128 rows x 512 B (2 hops worth of K)
    int tid = threadIdx.x;
    int w = tid >> 6, lane = tid & 63;
    int r16 = lane & 15, kg = lane >> 4;
    int tb = blockIdx.x * 128 + w * 32;   // wave tile base node; 100000 % 32 == 0
    bool active = (tb < NNODES);
    floatx4 acc[2][8];
#pragma unroll
    for (int s = 0; s < 2; s++)
#pragma unroll
        for (int n = 0; n < 8; n++) acc[s][n] = (floatx4){0.f, 0.f, 0.f, 0.f};
    const ushort_t* Ps[4] = {P0, P1, P2, P3};
    for (int stage = 0; stage < 2; stage++) {
        __syncthreads();   // protect LDS reuse across stages
#pragma unroll
        for (int i = 0; i < 16; i++) {
            int idx = i * 256 + tid;          // 16B-unit index, 4096 total
            int r = idx >> 5;                 // row 0..127
            int slot = idx & 31;
            int cb = (slot * 16) ^ ((r & 7) << 4);
            *(uint4*)((char*)Bs + r * 512 + cb) =
                *(const uint4*)(Wt + r * 512 + stage * 256 + slot * 8);
        }
        __syncthreads();
        if (active) {
#pragma unroll
            for (int hh = 0; hh < 2; hh++) {
                const ushort_t* P = Ps[stage * 2 + hh];
#pragma unroll
                for (int k0 = 0; k0 < 128; k0 += 32) {
                    int f = k0 + kg * 8;
                    const ushort_t* Pa = P + (f >> 4) * SLS + (f & 15);
                    short8 a0 = *(const short8*)(Pa + (tb + r16) * 16);
                    short8 a1 = *(const short8*)(Pa + (tb + 16 + r16) * 16);
#pragma unroll
                    for (int n = 0; n < 8; n++) {
                        int r = n * 16 + r16;
                        int cb = (hh * 256 + k0 * 2 + kg * 16) ^ ((r & 7) << 4);
                        short8 b = *(const short8*)((const char*)Bs + r * 512 + cb);
                        acc[0][n] = __builtin_amdgcn_mfma_f32_16x16x32_bf16(a0, b, acc[0][n], 0, 0, 0);
                        acc[1][n] = __builtin_amdgcn_mfma_f32_16x16x32_bf16(a1, b, acc[1][n], 0, 0, 0);
                    }
                }
            }
        }
    }
    if (!active) return;
    float bb[8];
#pragma unroll
    for (int n = 0; n < 8; n++) bb[n] = b2[n * 16 + r16];
    int g0 = batch[tb], g31 = batch[tb + 31];
    if (g0 == g31) {
#pragma unroll
        for (int n = 0; n < 8; n++) {
            float s = 0.0f;
#pragma unroll
            for (int st = 0; st < 2; st++)
#pragma unroll
                for (int r = 0; r < 4; r++) s += fmaxf(acc[st][n][r] + bb[n], 0.0f);
            s += __shfl_xor(s, 16);
            s += __shfl_xor(s, 32);
            if (kg == 0) atomicAdd(&sums[g0 * HID + n * 16 + r16], s);
        }
    } else {
#pragma unroll
        for (int st = 0; st < 2; st++)
#pragma unroll
            for (int r = 0; r < 4; r++) {
                int g = batch[tb + st * 16 + kg * 4 + r];
#pragma unroll
                for (int n = 0; n < 8; n++)
                    atomicAdd(&sums[g * HID + n * 16 + r16], fmaxf(acc[st][n][r] + bb[n], 0.0f));
            }
    }
}

// ---------------- head ----------------
__global__ void head_kernel(const float* __restrict__ sums, const int* __restrict__ first,
                            const int* __restrict__ last,
                            const float* __restrict__ Wlin, const float* __restrict__ blin,
                            float* __restrict__ out) {
    int g = threadIdx.x;
    if (g >= NGRAPHS) return;
    float cnt = (float)(last[g] - first[g] + 1);
    if (cnt < 1.0f) cnt = 1.0f;
    float l0 = blin[0], l1 = blin[1];
    for (int i = 0; i < HID; i++) {
        float p = sums[g * HID + i] / cnt;
        l0 += p * Wlin[i * 2 + 0];
        l1 += p * Wlin[i * 2 + 1];
    }
    float m = fmaxf(l0, l1);
    float e0 = __expf(l0 - m), e1 = __expf(l1 - m);
    float s = e0 + e1;
    out[g * 2 + 0] = e0 / s;
    out[g * 2 + 1] = e1 / s;
}

// ---------------- workspace layout (4-byte units) ----------------
#define OFF_DINV  0
#define OFF_DEGI  (OFF_DINV + NPAD)
#define OFF_OFF   (OFF_DEGI + NPAD)
// ---- single-memset region: sums, first, last, bcnt (contiguous) ----
#define OFF_SUMS  (OFF_OFF + NPAD)
#define OFF_FIRST (OFF_SUMS + NGRAPHS * HID)
#define OFF_LAST  (OFF_FIRST + NGRAPHS)
#define OFF_BCNT  (OFF_LAST + NGRAPHS)
#define ZERO_WORDS (NGRAPHS * HID + NGRAPHS + NGRAPHS + 800)
// ----
#define OFF_BBASE (OFF_BCNT + 800)
#define OFF_GC    (OFF_BBASE + 800)
#define OFF_ENT   (OFF_GC + 800)                  // uint[NEDGES]
#define OFF_SRC   (OFF_ENT + NEDGES)              // int[NEDGES]
#define OFF_EPK   (OFF_SRC + NEDGES)              // uint2[NEDGES] (8B aligned)
#define PSZ       (NPAD * HID / 2)                // sliced bf16 buffer: 8*NPAD*16*2B
#define OFF_P0    (OFF_EPK + 2 * NEDGES)
#define OFF_P1    (OFF_P0 + PSZ)
#define OFF_P2    (OFF_P1 + PSZ)
#define OFF_P3    (OFF_P2 + PSZ)
#define OFF_H1    (OFF_P3 + PSZ)
#define OFF_H2    (OFF_H1 + NNODES * 4)
#define OFF_H3    (OFF_H2 + NNODES * 4)
#define OFF_WT    (OFF_H3 + NNODES * 4)

extern "C" void kernel_launch(void* const* d_in, const int* in_sizes, int n_in,
                              void* d_out, int out_size, void* d_ws, size_t ws_size,
                              hipStream_t stream) {
    const float* x    = (const float*)d_in[0];
    const float* W1   = (const float*)d_in[1];
    const float* b1   = (const float*)d_in[2];
    const float* W2   = (const float*)d_in[3];
    const float* b2   = (const float*)d_in[4];
    const float* Wlin = (const float*)d_in[5];
    const float* blin = (const float*)d_in[6];
    const int* ei     = (const int*)d_in[7];
    const int* batch  = (const int*)d_in[8];
    float* out = (float*)d_out;

    const int* row = ei;
    const int* col = ei + NEDGES;

    float* ws = (float*)d_ws;
    float* dinv    = ws + OFF_DINV;
    int*   degi    = (int*)(ws + OFF_DEGI);
    int*   off     = (int*)(ws + OFF_OFF);
    float* sums    = ws + OFF_SUMS;
    int*   first   = (int*)(ws + OFF_FIRST);
    int*   last    = (int*)(ws + OFF_LAST);
    int*   bcnt    = (int*)(ws + OFF_BCNT);
    int*   bbase   = (int*)(ws + OFF_BBASE);
    int*   gc      = (int*)(ws + OFF_GC);
    uint_t* ent    = (uint_t*)(ws + OFF_ENT);
    int*   csr_src = (int*)(ws + OFF_SRC);
    uint2* epk     = (uint2*)(ws + OFF_EPK);
    ushort_t* P0   = (ushort_t*)(ws + OFF_P0);
    ushort_t* P1   = (ushort_t*)(ws + OFF_P1);
    ushort_t* P2   = (ushort_t*)(ws + OFF_P2);
    ushort_t* P3   = (ushort_t*)(ws + OFF_P3);
    float* h1      = ws + OFF_H1;
    float* h2      = ws + OFF_H2;
    float* h3      = ws + OFF_H3;
    ushort_t* Wt   = (ushort_t*)(ws + OFF_WT);

    // ---- init (single memset: sums + first + last + bcnt) ----
    hipMemsetAsync(sums, 0, ZERO_WORDS * sizeof(float), stream);

    // ---- CSR build (bucket counting sort) ----
    hist_k<<<NCHB, 256, 0, stream>>>(col, bcnt);
    bscan_k<<<1, 1024, 0, stream>>>(bcnt, bbase, gc);
    bfill_k<<<NCHB, 256, 0, stream>>>(row, col, gc, ent);
    sortb_k<<<NBKT, 256, 0, stream>>>(ent, bbase, csr_src, degi, off);
    misc_k<<<NPAD / 256, 256, 0, stream>>>(degi, dinv, W2, Wt, batch, first, last);
    wfill_k<<<NPAD / 256, 256, 0, stream>>>(off, csr_src, dinv, epk);

    // ---- layer 1 (fp32, F=4) ----
    gprop4<<<NPAD / 256, 256, 0, stream>>>(off, epk, x, h1);
    gprop4<<<NPAD / 256, 256, 0, stream>>>(off, epk, h1, h2);
    gprop4<<<NPAD / 256, 256, 0, stream>>>(off, epk, h2, h3);
    combine1<<<NNODES / 4, 128, 0, stream>>>(x, h1, h2, h3, W1, b1, P0);

    // ---- layer 2 hops (bf16, XCD-pinned feature slices) ----
    gprop128s<<<NBKT * NSL, 256, 0, stream>>>(off, epk, P0, P1);
    gprop128s<<<NBKT * NSL, 256, 0, stream>>>(off, epk, P1, P2);
    gprop128s<<<NBKT * NSL, 256, 0, stream>>>(off, epk, P2, P3);

    // ---- fused MFMA combine + pool (K=512, B in LDS) ----
    gemm4p<<<(NNODES + 127) / 128, 256, 0, stream>>>(P0, P1, P2, P3, Wt, b2, batch, sums);

    // ---- head ----
    head_kernel<<<1, 128, 0, stream>>>(sums, first, last, Wlin, blin, out);
}

// Round 12
// 433.379 us; speedup vs baseline: 1.7685x; 1.7685x over previous
//
#include <hip/hip_runtime.h>

#define NNODES 100000
#define NEDGES 1600000
#define NGRAPHS 128
#define HID 128
#define NBKT 782            // ceil(100000/128)
#define NPAD  (NBKT * 128)  // 100096
#define CHUNK 8192
#define NCHB ((NEDGES + CHUNK - 1) / CHUNK)   // 196
#define MAXB 3072           // bucket edge cap (mean 2048, sigma ~45)

typedef unsigned short ushort_t;
typedef unsigned int uint_t;
typedef unsigned long long u64;
typedef __attribute__((ext_vector_type(8))) short short8;
typedef __attribute__((ext_vector_type(4))) float floatx4;
typedef __attribute__((ext_vector_type(4))) unsigned int uint4e;

__device__ __forceinline__ float bf2f(ushort_t u) {
    return __uint_as_float(((unsigned)u) << 16);
}
__device__ __forceinline__ ushort_t f2bf(float f) {
    unsigned u = __float_as_uint(f);
    return (ushort_t)((u + 0x7fffu + ((u >> 16) & 1u)) >> 16);
}

// ---------------- bucket histogram (LDS-staged) ----------------
__global__ void hist_k(const int* __restrict__ col, int* __restrict__ bcnt) {
    __shared__ int l[NBKT];
    for (int i = threadIdx.x; i < NBKT; i += 256) l[i] = 0;
    __syncthreads();
    int base = blockIdx.x * CHUNK;
    int lim = base + CHUNK < NEDGES ? base + CHUNK : NEDGES;
    for (int e = base + threadIdx.x; e < lim; e += 256)
        atomicAdd(&l[col[e] >> 7], 1);
    __syncthreads();
    for (int i = threadIdx.x; i < NBKT; i += 256)
        if (l[i]) atomicAdd(&bcnt[i], l[i]);
}

// ---------------- scan 782 buckets (single block) ----------------
__global__ void bscan_k(const int* __restrict__ bcnt, int* __restrict__ bbase,
                        int* __restrict__ gc) {
    __shared__ int l[1024];
    int t = threadIdx.x;
    int v0 = (t < NBKT) ? bcnt[t] : 0;
    l[t] = v0;
    __syncthreads();
    for (int d = 1; d < 1024; d <<= 1) {
        int v = (t >= d) ? l[t - d] : 0;
        __syncthreads();
        l[t] += v;
        __syncthreads();
    }
    if (t < NBKT) { int ex = l[t] - v0; bbase[t] = ex; gc[t] = ex; }
    if (t == 0) bbase[NBKT] = NEDGES;
}

// ---------------- bucket scatter: one range-claim atomic per (block,bucket) ----------------
__global__ void bfill_k(const int* __restrict__ row, const int* __restrict__ col,
                        int* __restrict__ gc, uint_t* __restrict__ entry) {
    __shared__ int lcnt[NBKT], lbase[NBKT];
    for (int i = threadIdx.x; i < NBKT; i += 256) lcnt[i] = 0;
    __syncthreads();
    int base = blockIdx.x * CHUNK;
    int lim = base + CHUNK < NEDGES ? base + CHUNK : NEDGES;
    for (int e = base + threadIdx.x; e < lim; e += 256)
        atomicAdd(&lcnt[col[e] >> 7], 1);
    __syncthreads();
    for (int i = threadIdx.x; i < NBKT; i += 256) {
        int c = lcnt[i];
        lbase[i] = c ? atomicAdd(&gc[i], c) : 0;
        lcnt[i] = 0;   // reuse as fill cursor
    }
    __syncthreads();
    for (int e = base + threadIdx.x; e < lim; e += 256) {
        int c = col[e];
        int b = c >> 7;
        int pos = lbase[b] + atomicAdd(&lcnt[b], 1);
        entry[pos] = (uint_t)row[e] | ((uint_t)(c & 127) << 17);
    }
}

// ---------------- per-bucket LDS counting sort -> csr_src, degi->dinv, off ----------------
__global__ void sortb_k(const uint_t* __restrict__ entry, const int* __restrict__ bbase,
                        int* __restrict__ csr_src, float* __restrict__ dinv,
                        int* __restrict__ off) {
    __shared__ uint_t ents[MAXB];
    __shared__ uint_t sorted[MAXB];
    __shared__ int ncnt[128], nsc[128], nfill[128];
    int b = blockIdx.x;
    int base = bbase[b];
    int cnt = bbase[b + 1] - base;
    if (cnt > MAXB) cnt = MAXB;
    int t = threadIdx.x;
    if (t < 128) { ncnt[t] = 0; nfill[t] = 0; }
    __syncthreads();
    for (int i = t; i < cnt; i += 256) {
        uint_t v = entry[base + i];
        ents[i] = v;
        atomicAdd(&ncnt[v >> 17], 1);
    }
    __syncthreads();
    if (t < 128) nsc[t] = ncnt[t];
    __syncthreads();
    for (int d = 1; d < 128; d <<= 1) {
        int v = (t >= d && t < 128) ? nsc[t - d] : 0;
        __syncthreads();
        if (t < 128) nsc[t] += v;   // inclusive scan
        __syncthreads();
    }
    if (t < 128) {
        int n = b * 128 + t;
        if (n < NNODES) {
            off[n] = base + nsc[t];
            dinv[n] = (ncnt[t] > 0) ? rsqrtf((float)ncnt[t]) : 0.0f;
        }
        nsc[t] -= ncnt[t];          // exclusive
    }
    __syncthreads();
    for (int i = t; i < cnt; i += 256) {
        uint_t v = ents[i];
        int dl = v >> 17;
        int pos = nsc[dl] + atomicAdd(&nfill[dl], 1);
        sorted[pos] = v & 0x1FFFFu;
    }
    __syncthreads();
    for (int i = t; i < cnt; i += 256) csr_src[base + i] = (int)sorted[i];
}

// ---------------- fused: Wt transpose + graph bounds ----------------
__global__ void misc_k(const float* __restrict__ W2, ushort_t* __restrict__ Wt,
                       const int* __restrict__ batch,
                       int* __restrict__ first, int* __restrict__ last) {
    int i = blockIdx.x * 256 + threadIdx.x;
    if (i < NNODES) {
        int g = batch[i];
        if (i == 0 || batch[i - 1] != g) first[g] = i;
        if (i == NNODES - 1 || batch[i + 1] != g) last[g] = i;
    }
    if (i < 512 * 128) {
        int j = i >> 9, k = i & 511;
        Wt[i] = f2bf(W2[k * 128 + j]);   // Wt[j][k], k = hop*128+i
    }
}

// ---------------- layer-1 hop 1 (x -> h1) + emit packed edges epk ----------------
__global__ void gprop4w(const int* __restrict__ off, const int* __restrict__ csr_src,
                        const float* __restrict__ dinv,
                        const float* __restrict__ hin, float* __restrict__ hout,
                        uint2* __restrict__ epk) {
    int n = blockIdx.x * 256 + threadIdx.x;
    if (n >= NNODES) return;
    int k = n ? off[n - 1] : 0;
    int end = off[n];
    float dn = dinv[n];
    float4 acc = {0.f, 0.f, 0.f, 0.f};
    for (; k < end; k++) {
        int s = csr_src[k];
        float w = dinv[s] * dn;
        epk[k] = make_uint2((uint_t)s, __float_as_uint(w));
        float4 v = *(const float4*)(hin + s * 4);
        acc.x += w * v.x; acc.y += w * v.y; acc.z += w * v.z; acc.w += w * v.w;
    }
    *(float4*)(hout + n * 4) = acc;
}

// ---------------- layer-1 gather (F=4, fp32), packed edges, unroll 4 ----------------
__global__ void gprop4(const int* __restrict__ off, const uint2* __restrict__ epk,
                       const float* __restrict__ hin, float* __restrict__ hout) {
    int n = blockIdx.x * 256 + threadIdx.x;
    if (n >= NNODES) return;
    int k = n ? off[n - 1] : 0;
    int end = off[n];
    float4 acc = {0.f, 0.f, 0.f, 0.f};
    for (; k + 3 < end; k += 4) {
        uint2 e0 = epk[k], e1 = epk[k + 1], e2 = epk[k + 2], e3 = epk[k + 3];
        float w0 = __uint_as_float(e0.y), w1 = __uint_as_float(e1.y);
        float w2 = __uint_as_float(e2.y), w3 = __uint_as_float(e3.y);
        float4 v0 = *(const float4*)(hin + e0.x * 4);
        float4 v1 = *(const float4*)(hin + e1.x * 4);
        float4 v2 = *(const float4*)(hin + e2.x * 4);
        float4 v3 = *(const float4*)(hin + e3.x * 4);
        acc.x += w0 * v0.x + w1 * v1.x + w2 * v2.x + w3 * v3.x;
        acc.y += w0 * v0.y + w1 * v1.y + w2 * v2.y + w3 * v3.y;
        acc.z += w0 * v0.z + w1 * v1.z + w2 * v2.z + w3 * v3.z;
        acc.w += w0 * v0.w + w1 * v1.w + w2 * v2.w + w3 * v3.w;
    }
    for (; k < end; k++) {
        uint2 e = epk[k];
        float w = __uint_as_float(e.y);
        float4 v = *(const float4*)(hin + e.x * 4);
        acc.x += w * v.x; acc.y += w * v.y; acc.z += w * v.z; acc.w += w * v.w;
    }
    *(float4*)(hout + n * 4) = acc;
}

// ---------------- layer-2 gather helper: acc8 += wgt * bf16x8(v) ----------------
__device__ __forceinline__ void acc8(float* a, float wgt, uint4 v) {
    a[0] += wgt * __uint_as_float(v.x << 16);
    a[1] += wgt * __uint_as_float(v.x & 0xffff0000u);
    a[2] += wgt * __uint_as_float(v.y << 16);
    a[3] += wgt * __uint_as_float(v.y & 0xffff0000u);
    a[4] += wgt * __uint_as_float(v.z << 16);
    a[5] += wgt * __uint_as_float(v.z & 0xffff0000u);
    a[6] += wgt * __uint_as_float(v.w << 16);
    a[7] += wgt * __uint_as_float(v.w & 0xffff0000u);
}

// ---------------- layer-2 gather (F=128 bf16), 16 lanes/node, unroll 4 ----------------
// epk loads + output stores are NONTEMPORAL so the 25.6MB P-table keeps L2 room.
__global__ void gprop128(const int* __restrict__ off, const uint2* __restrict__ epk,
                         const ushort_t* __restrict__ hin, ushort_t* __restrict__ hout) {
    int t = blockIdx.x * 256 + threadIdx.x;
    int n = t >> 4, lane = t & 15;
    if (n >= NNODES) return;
    int k = n ? off[n - 1] : 0;
    int end = off[n];
    int fo = lane * 8;
    float a[8] = {0.f, 0.f, 0.f, 0.f, 0.f, 0.f, 0.f, 0.f};
    const u64* ep = (const u64*)epk;
    for (; k + 3 < end; k += 4) {
        u64 e0 = __builtin_nontemporal_load(ep + k);
        u64 e1 = __builtin_nontemporal_load(ep + k + 1);
        u64 e2 = __builtin_nontemporal_load(ep + k + 2);
        u64 e3 = __builtin_nontemporal_load(ep + k + 3);
        uint4 v0 = *(const uint4*)(hin + (uint_t)(e0 & 0xffffffffu) * HID + fo);
        uint4 v1 = *(const uint4*)(hin + (uint_t)(e1 & 0xffffffffu) * HID + fo);
        uint4 v2 = *(const uint4*)(hin + (uint_t)(e2 & 0xffffffffu) * HID + fo);
        uint4 v3 = *(const uint4*)(hin + (uint_t)(e3 & 0xffffffffu) * HID + fo);
        acc8(a, __uint_as_float((uint_t)(e0 >> 32)), v0);
        acc8(a, __uint_as_float((uint_t)(e1 >> 32)), v1);
        acc8(a, __uint_as_float((uint_t)(e2 >> 32)), v2);
        acc8(a, __uint_as_float((uint_t)(e3 >> 32)), v3);
    }
    for (; k < end; k++) {
        u64 e = __builtin_nontemporal_load(ep + k);
        uint4 v = *(const uint4*)(hin + (uint_t)(e & 0xffffffffu) * HID + fo);
        acc8(a, __uint_as_float((uint_t)(e >> 32)), v);
    }
    uint4e o;
    o.x = (unsigned)f2bf(a[0]) | ((unsigned)f2bf(a[1]) << 16);
    o.y = (unsigned)f2bf(a[2]) | ((unsigned)f2bf(a[3]) << 16);
    o.z = (unsigned)f2bf(a[4]) | ((unsigned)f2bf(a[5]) << 16);
    o.w = (unsigned)f2bf(a[6]) | ((unsigned)f2bf(a[7]) << 16);
    __builtin_nontemporal_store(o, (uint4e*)(hout + n * HID + fo));
}

// ---------------- layer-1 combine -> bf16 P0 ----------------
__global__ void combine1(const float* __restrict__ x, const float* __restrict__ h1,
                         const float* __restrict__ h2, const float* __restrict__ h3,
                         const float* __restrict__ W1, const float* __restrict__ b1,
                         ushort_t* __restrict__ P0) {
    __shared__ float hs[4][16];
    int n0 = blockIdx.x * 4;
    int j = threadIdx.x;  // 0..127
    if (j < 64) {
        int n = j >> 4, v = j & 15, k = v >> 2, i = v & 3;
        const float* src = (k == 0) ? x : (k == 1) ? h1 : (k == 2) ? h2 : h3;
        hs[n][v] = src[(n0 + n) * 4 + i];
    }
    __syncthreads();
    float w[16];
#pragma unroll
    for (int v = 0; v < 16; v++) w[v] = W1[v * 128 + j];
    float bb = b1[j];
#pragma unroll
    for (int n = 0; n < 4; n++) {
        float acc = bb;
#pragma unroll
        for (int v = 0; v < 16; v++) acc += hs[n][v] * w[v];
        P0[(n0 + n) * 128 + j] = f2bf(fmaxf(acc, 0.0f));
    }
}

// ---------------- fused MFMA + pool, B staged in LDS ----------------
__global__ __launch_bounds__(256) void gemm4p(
    const ushort_t* __restrict__ P0, const ushort_t* __restrict__ P1,
    const ushort_t* __restrict__ P2, const ushort_t* __restrict__ P3,
    const ushort_t* __restrict__ Wt, const float* __restrict__ b2,
    const int* __restrict__ batch, float* __restrict__ sums) {
    __shared__ ushort_t Bs[32768];   // 64 KB: 128 rows x 512 B (2 hops worth of K)
    int tid = threadIdx.x;
    int w = tid >> 6, lane = tid & 63;
    int r16 = lane & 15, kg = lane >> 4;
    int tb = blockIdx.x * 128 + w * 32;   // wave tile base node; 100000 % 32 == 0
    bool active = (tb < NNODES);
    floatx4 acc[2][8];
#pragma unroll
    for (int s = 0; s < 2; s++)
#pragma unroll
        for (int n = 0; n < 8; n++) acc[s][n] = (floatx4){0.f, 0.f, 0.f, 0.f};
    const ushort_t* Ps[4] = {P0, P1, P2, P3};
    for (int stage = 0; stage < 2; stage++) {
        __syncthreads();   // protect LDS reuse across stages
#pragma unroll
        for (int i = 0; i < 16; i++) {
            int idx = i * 256 + tid;          // 16B-unit index, 4096 total
            int r = idx >> 5;                 // row 0..127
            int slot = idx & 31;
            int cb = (slot * 16) ^ ((r & 7) << 4);
            *(uint4*)((char*)Bs + r * 512 + cb) =
                *(const uint4*)(Wt + r * 512 + stage * 256 + slot * 8);
        }
        __syncthreads();
        if (active) {
#pragma unroll
            for (int hh = 0; hh < 2; hh++) {
                const ushort_t* P = Ps[stage * 2 + hh];
#pragma unroll
                for (int k0 = 0; k0 < 128; k0 += 32) {
                    int f = k0 + kg * 8;
                    short8 a0 = *(const short8*)(P + (tb + r16) * HID + f);
                    short8 a1 = *(const short8*)(P + (tb + 16 + r16) * HID + f);
#pragma unroll
                    for (int n = 0; n < 8; n++) {
                        int r = n * 16 + r16;
                        int cb = (hh * 256 + k0 * 2 + kg * 16) ^ ((r & 7) << 4);
                        short8 b = *(const short8*)((const char*)Bs + r * 512 + cb);
                        acc[0][n] = __builtin_amdgcn_mfma_f32_16x16x32_bf16(a0, b, acc[0][n], 0, 0, 0);
                        acc[1][n] = __builtin_amdgcn_mfma_f32_16x16x32_bf16(a1, b, acc[1][n], 0, 0, 0);
                    }
                }
            }
        }
    }
    if (!active) return;
    float bb[8];
#pragma unroll
    for (int n = 0; n < 8; n++) bb[n] = b2[n * 16 + r16];
    int g0 = batch[tb], g31 = batch[tb + 31];
    if (g0 == g31) {
#pragma unroll
        for (int n = 0; n < 8; n++) {
            float s = 0.0f;
#pragma unroll
            for (int st = 0; st < 2; st++)
#pragma unroll
                for (int r = 0; r < 4; r++) s += fmaxf(acc[st][n][r] + bb[n], 0.0f);
            s += __shfl_xor(s, 16);
            s += __shfl_xor(s, 32);
            if (kg == 0) atomicAdd(&sums[g0 * HID + n * 16 + r16], s);
        }
    } else {
#pragma unroll
        for (int st = 0; st < 2; st++)
#pragma unroll
            for (int r = 0; r < 4; r++) {
                int g = batch[tb + st * 16 + kg * 4 + r];
#pragma unroll
                for (int n = 0; n < 8; n++)
                    atomicAdd(&sums[g * HID + n * 16 + r16], fmaxf(acc[st][n][r] + bb[n], 0.0f));
            }
    }
}

// ---------------- head ----------------
__global__ void head_kernel(const float* __restrict__ sums, const int* __restrict__ first,
                            const int* __restrict__ last,
                            const float* __restrict__ Wlin, const float* __restrict__ blin,
                            float* __restrict__ out) {
    int g = threadIdx.x;
    if (g >= NGRAPHS) return;
    float cnt = (float)(last[g] - first[g] + 1);
    if (cnt < 1.0f) cnt = 1.0f;
    float l0 = blin[0], l1 = blin[1];
    for (int i = 0; i < HID; i++) {
        float p = sums[g * HID + i] / cnt;
        l0 += p * Wlin[i * 2 + 0];
        l1 += p * Wlin[i * 2 + 1];
    }
    float m = fmaxf(l0, l1);
    float e0 = __expf(l0 - m), e1 = __expf(l1 - m);
    float s = e0 + e1;
    out[g * 2 + 0] = e0 / s;
    out[g * 2 + 1] = e1 / s;
}

// ---------------- workspace layout (4-byte units) ----------------
#define OFF_DINV  0
#define OFF_OFF   (OFF_DINV + NPAD)
// ---- single-memset region: sums, first, last, bcnt (contiguous) ----
#define OFF_SUMS  (OFF_OFF + NPAD)
#define OFF_FIRST (OFF_SUMS + NGRAPHS * HID)
#define OFF_LAST  (OFF_FIRST + NGRAPHS)
#define OFF_BCNT  (OFF_LAST + NGRAPHS)
#define ZERO_WORDS (NGRAPHS * HID + NGRAPHS + NGRAPHS + 800)
// ----
#define OFF_BBASE (OFF_BCNT + 800)
#define OFF_GC    (OFF_BBASE + 800)
#define OFF_ENT   (OFF_GC + 800)                  // uint[NEDGES]
#define OFF_SRC   (OFF_ENT + NEDGES)              // int[NEDGES]
#define OFF_EPK   (OFF_SRC + NEDGES)              // uint2[NEDGES] (8B aligned)
#define OFF_P0    (OFF_EPK + 2 * NEDGES)
#define OFF_P1    (OFF_P0 + NNODES * HID / 2)     // bf16 [N,128] = N*64 words
#define OFF_P2    (OFF_P1 + NNODES * HID / 2)
#define OFF_P3    (OFF_P2 + NNODES * HID / 2)
#define OFF_H1    (OFF_P3 + NNODES * HID / 2)
#define OFF_H2    (OFF_H1 + NNODES * 4)
#define OFF_H3    (OFF_H2 + NNODES * 4)
#define OFF_WT    (OFF_H3 + NNODES * 4)

extern "C" void kernel_launch(void* const* d_in, const int* in_sizes, int n_in,
                              void* d_out, int out_size, void* d_ws, size_t ws_size,
                              hipStream_t stream) {
    const float* x    = (const float*)d_in[0];
    const float* W1   = (const float*)d_in[1];
    const float* b1   = (const float*)d_in[2];
    const float* W2   = (const float*)d_in[3];
    const float* b2   = (const float*)d_in[4];
    const float* Wlin = (const float*)d_in[5];
    const float* blin = (const float*)d_in[6];
    const int* ei     = (const int*)d_in[7];
    const int* batch  = (const int*)d_in[8];
    float* out = (float*)d_out;

    const int* row = ei;
    const int* col = ei + NEDGES;

    float* ws = (float*)d_ws;
    float* dinv    = ws + OFF_DINV;
    int*   off     = (int*)(ws + OFF_OFF);
    float* sums    = ws + OFF_SUMS;
    int*   first   = (int*)(ws + OFF_FIRST);
    int*   last    = (int*)(ws + OFF_LAST);
    int*   bcnt    = (int*)(ws + OFF_BCNT);
    int*   bbase   = (int*)(ws + OFF_BBASE);
    int*   gc      = (int*)(ws + OFF_GC);
    uint_t* ent    = (uint_t*)(ws + OFF_ENT);
    int*   csr_src = (int*)(ws + OFF_SRC);
    uint2* epk     = (uint2*)(ws + OFF_EPK);
    ushort_t* P0   = (ushort_t*)(ws + OFF_P0);
    ushort_t* P1   = (ushort_t*)(ws + OFF_P1);
    ushort_t* P2   = (ushort_t*)(ws + OFF_P2);
    ushort_t* P3   = (ushort_t*)(ws + OFF_P3);
    float* h1      = ws + OFF_H1;
    float* h2      = ws + OFF_H2;
    float* h3      = ws + OFF_H3;
    ushort_t* Wt   = (ushort_t*)(ws + OFF_WT);

    // ---- init (single memset: sums + first + last + bcnt) ----
    hipMemsetAsync(sums, 0, ZERO_WORDS * sizeof(float), stream);

    // ---- CSR build (bucket counting sort; sortb also emits dinv) ----
    hist_k<<<NCHB, 256, 0, stream>>>(col, bcnt);
    bscan_k<<<1, 1024, 0, stream>>>(bcnt, bbase, gc);
    bfill_k<<<NCHB, 256, 0, stream>>>(row, col, gc, ent);
    sortb_k<<<NBKT, 256, 0, stream>>>(ent, bbase, csr_src, dinv, off);
    misc_k<<<NPAD / 256, 256, 0, stream>>>(W2, Wt, batch, first, last);

    // ---- layer 1 (fp32, F=4); hop 1 also emits packed edges epk ----
    gprop4w<<<NPAD / 256, 256, 0, stream>>>(off, csr_src, dinv, x, h1, epk);
    gprop4<<<NPAD / 256, 256, 0, stream>>>(off, epk, h1, h2);
    gprop4<<<NPAD / 256, 256, 0, stream>>>(off, epk, h2, h3);
    combine1<<<NNODES / 4, 128, 0, stream>>>(x, h1, h2, h3, W1, b1, P0);

    // ---- layer 2 hops (bf16) ----
    gprop128<<<NPAD * 16 / 256, 256, 0, stream>>>(off, epk, P0, P1);
    gprop128<<<NPAD * 16 / 256, 256, 0, stream>>>(off, epk, P1, P2);
    gprop128<<<NPAD * 16 / 256, 256, 0, stream>>>(off, epk, P2, P3);

    // ---- fused MFMA combine + pool (K=512, B in LDS) ----
    gemm4p<<<(NNODES + 127) / 128, 256, 0, stream>>>(P0, P1, P2, P3, Wt, b2, batch, sums);

    // ---- head ----
    head_kernel<<<1, 128, 0, stream>>>(sums, first, last, Wlin, blin, out);
}

// Round 13
// 363.744 us; speedup vs baseline: 2.1071x; 1.1914x over previous
//
#include <hip/hip_runtime.h>

#define NNODES 100000
#define NEDGES 1600000
#define NGRAPHS 128
#define HID 128
#define NBKT 782            // ceil(100000/128)
#define NPAD  (NBKT * 128)  // 100096
#define CHUNK 8192
#define NCHB ((NEDGES + CHUNK - 1) / CHUNK)   // 196
#define MAXB 3072           // bucket edge cap (mean 2048, sigma ~45)

typedef unsigned short ushort_t;
typedef unsigned int uint_t;
typedef __attribute__((ext_vector_type(8))) short short8;
typedef __attribute__((ext_vector_type(4))) float floatx4;

__device__ __forceinline__ float bf2f(ushort_t u) {
    return __uint_as_float(((unsigned)u) << 16);
}
__device__ __forceinline__ ushort_t f2bf(float f) {
    unsigned u = __float_as_uint(f);
    return (ushort_t)((u + 0x7fffu + ((u >> 16) & 1u)) >> 16);
}

// ---------------- bucket histogram (LDS-staged) ----------------
__global__ void hist_k(const int* __restrict__ col, int* __restrict__ bcnt) {
    __shared__ int l[NBKT];
    for (int i = threadIdx.x; i < NBKT; i += 256) l[i] = 0;
    __syncthreads();
    int base = blockIdx.x * CHUNK;
    int lim = base + CHUNK < NEDGES ? base + CHUNK : NEDGES;
    for (int e = base + threadIdx.x; e < lim; e += 256)
        atomicAdd(&l[col[e] >> 7], 1);
    __syncthreads();
    for (int i = threadIdx.x; i < NBKT; i += 256)
        if (l[i]) atomicAdd(&bcnt[i], l[i]);
}

// ---------------- scan 782 buckets (single block) ----------------
__global__ void bscan_k(const int* __restrict__ bcnt, int* __restrict__ bbase,
                        int* __restrict__ gc) {
    __shared__ int l[1024];
    int t = threadIdx.x;
    int v0 = (t < NBKT) ? bcnt[t] : 0;
    l[t] = v0;
    __syncthreads();
    for (int d = 1; d < 1024; d <<= 1) {
        int v = (t >= d) ? l[t - d] : 0;
        __syncthreads();
        l[t] += v;
        __syncthreads();
    }
    if (t < NBKT) { int ex = l[t] - v0; bbase[t] = ex; gc[t] = ex; }
    if (t == 0) bbase[NBKT] = NEDGES;
}

// ---------------- bucket scatter: one range-claim atomic per (block,bucket) ----------------
__global__ void bfill_k(const int* __restrict__ row, const int* __restrict__ col,
                        int* __restrict__ gc, uint_t* __restrict__ entry) {
    __shared__ int lcnt[NBKT], lbase[NBKT];
    for (int i = threadIdx.x; i < NBKT; i += 256) lcnt[i] = 0;
    __syncthreads();
    int base = blockIdx.x * CHUNK;
    int lim = base + CHUNK < NEDGES ? base + CHUNK : NEDGES;
    for (int e = base + threadIdx.x; e < lim; e += 256)
        atomicAdd(&lcnt[col[e] >> 7], 1);
    __syncthreads();
    for (int i = threadIdx.x; i < NBKT; i += 256) {
        int c = lcnt[i];
        lbase[i] = c ? atomicAdd(&gc[i], c) : 0;
        lcnt[i] = 0;   // reuse as fill cursor
    }
    __syncthreads();
    for (int e = base + threadIdx.x; e < lim; e += 256) {
        int c = col[e];
        int b = c >> 7;
        int pos = lbase[b] + atomicAdd(&lcnt[b], 1);
        entry[pos] = (uint_t)row[e] | ((uint_t)(c & 127) << 17);
    }
}

// ---------------- per-bucket LDS counting sort -> csr_src, dinv, off ----------------
__global__ void sortb_k(const uint_t* __restrict__ entry, const int* __restrict__ bbase,
                        int* __restrict__ csr_src, float* __restrict__ dinv,
                        int* __restrict__ off) {
    __shared__ uint_t ents[MAXB];
    __shared__ uint_t sorted[MAXB];
    __shared__ int ncnt[128], nsc[128], nfill[128];
    int b = blockIdx.x;
    int base = bbase[b];
    int cnt = bbase[b + 1] - base;
    if (cnt > MAXB) cnt = MAXB;
    int t = threadIdx.x;
    if (t < 128) { ncnt[t] = 0; nfill[t] = 0; }
    __syncthreads();
    for (int i = t; i < cnt; i += 256) {
        uint_t v = entry[base + i];
        ents[i] = v;
        atomicAdd(&ncnt[v >> 17], 1);
    }
    __syncthreads();
    if (t < 128) nsc[t] = ncnt[t];
    __syncthreads();
    for (int d = 1; d < 128; d <<= 1) {
        int v = (t >= d && t < 128) ? nsc[t - d] : 0;
        __syncthreads();
        if (t < 128) nsc[t] += v;   // inclusive scan
        __syncthreads();
    }
    if (t < 128) {
        int n = b * 128 + t;
        if (n < NNODES) {
            off[n] = base + nsc[t];
            dinv[n] = (ncnt[t] > 0) ? rsqrtf((float)ncnt[t]) : 0.0f;
        }
        nsc[t] -= ncnt[t];          // exclusive
    }
    __syncthreads();
    for (int i = t; i < cnt; i += 256) {
        uint_t v = ents[i];
        int dl = v >> 17;
        int pos = nsc[dl] + atomicAdd(&nfill[dl], 1);
        sorted[pos] = v & 0x1FFFFu;
    }
    __syncthreads();
    for (int i = t; i < cnt; i += 256) csr_src[base + i] = (int)sorted[i];
}

// ---------------- fused: Wt transpose + graph bounds ----------------
__global__ void misc_k(const float* __restrict__ W2, ushort_t* __restrict__ Wt,
                       const int* __restrict__ batch,
                       int* __restrict__ first, int* __restrict__ last) {
    int i = blockIdx.x * 256 + threadIdx.x;
    if (i < NNODES) {
        int g = batch[i];
        if (i == 0 || batch[i - 1] != g) first[g] = i;
        if (i == NNODES - 1 || batch[i + 1] != g) last[g] = i;
    }
    if (i < 512 * 128) {
        int j = i >> 9, k = i & 511;
        Wt[i] = f2bf(W2[k * 128 + j]);   // Wt[j][k], k = hop*128+i
    }
}

// ---------------- layer-1 hop 1 (x -> h1) + emit packed edges epk ----------------
__global__ void gprop4w(const int* __restrict__ off, const int* __restrict__ csr_src,
                        const float* __restrict__ dinv,
                        const float* __restrict__ hin, float* __restrict__ hout,
                        uint2* __restrict__ epk) {
    int n = blockIdx.x * 256 + threadIdx.x;
    if (n >= NNODES) return;
    int k = n ? off[n - 1] : 0;
    int end = off[n];
    float dn = dinv[n];
    float4 acc = {0.f, 0.f, 0.f, 0.f};
    for (; k + 1 < end; k += 2) {
        int s0 = csr_src[k], s1 = csr_src[k + 1];
        float w0 = dinv[s0] * dn, w1 = dinv[s1] * dn;
        epk[k]     = make_uint2((uint_t)s0, __float_as_uint(w0));
        epk[k + 1] = make_uint2((uint_t)s1, __float_as_uint(w1));
        float4 v0 = *(const float4*)(hin + s0 * 4);
        float4 v1 = *(const float4*)(hin + s1 * 4);
        acc.x += w0 * v0.x + w1 * v1.x;
        acc.y += w0 * v0.y + w1 * v1.y;
        acc.z += w0 * v0.z + w1 * v1.z;
        acc.w += w0 * v0.w + w1 * v1.w;
    }
    if (k < end) {
        int s = csr_src[k];
        float w = dinv[s] * dn;
        epk[k] = make_uint2((uint_t)s, __float_as_uint(w));
        float4 v = *(const float4*)(hin + s * 4);
        acc.x += w * v.x; acc.y += w * v.y; acc.z += w * v.z; acc.w += w * v.w;
    }
    *(float4*)(hout + n * 4) = acc;
}

// ---------------- layer-1 gather (F=4, fp32), packed edges, unroll 4 ----------------
__global__ void gprop4(const int* __restrict__ off, const uint2* __restrict__ epk,
                       const float* __restrict__ hin, float* __restrict__ hout) {
    int n = blockIdx.x * 256 + threadIdx.x;
    if (n >= NNODES) return;
    int k = n ? off[n - 1] : 0;
    int end = off[n];
    float4 acc = {0.f, 0.f, 0.f, 0.f};
    for (; k + 3 < end; k += 4) {
        uint2 e0 = epk[k], e1 = epk[k + 1], e2 = epk[k + 2], e3 = epk[k + 3];
        float w0 = __uint_as_float(e0.y), w1 = __uint_as_float(e1.y);
        float w2 = __uint_as_float(e2.y), w3 = __uint_as_float(e3.y);
        float4 v0 = *(const float4*)(hin + e0.x * 4);
        float4 v1 = *(const float4*)(hin + e1.x * 4);
        float4 v2 = *(const float4*)(hin + e2.x * 4);
        float4 v3 = *(const float4*)(hin + e3.x * 4);
        acc.x += w0 * v0.x + w1 * v1.x + w2 * v2.x + w3 * v3.x;
        acc.y += w0 * v0.y + w1 * v1.y + w2 * v2.y + w3 * v3.y;
        acc.z += w0 * v0.z + w1 * v1.z + w2 * v2.z + w3 * v3.z;
        acc.w += w0 * v0.w + w1 * v1.w + w2 * v2.w + w3 * v3.w;
    }
    for (; k < end; k++) {
        uint2 e = epk[k];
        float w = __uint_as_float(e.y);
        float4 v = *(const float4*)(hin + e.x * 4);
        acc.x += w * v.x; acc.y += w * v.y; acc.z += w * v.z; acc.w += w * v.w;
    }
    *(float4*)(hout + n * 4) = acc;
}

// ---------------- layer-2 gather helper: acc8 += wgt * bf16x8(v) ----------------
__device__ __forceinline__ void acc8(float* a, float wgt, uint4 v) {
    a[0] += wgt * __uint_as_float(v.x << 16);
    a[1] += wgt * __uint_as_float(v.x & 0xffff0000u);
    a[2] += wgt * __uint_as_float(v.y << 16);
    a[3] += wgt * __uint_as_float(v.y & 0xffff0000u);
    a[4] += wgt * __uint_as_float(v.z << 16);
    a[5] += wgt * __uint_as_float(v.z & 0xffff0000u);
    a[6] += wgt * __uint_as_float(v.w << 16);
    a[7] += wgt * __uint_as_float(v.w & 0xffff0000u);
}

// ---------------- layer-2 gather (F=128 bf16), 16 lanes/node, unroll 4 (r10 inner loop) ----------------
__global__ void gprop128(const int* __restrict__ off, const uint2* __restrict__ epk,
                         const ushort_t* __restrict__ hin, ushort_t* __restrict__ hout) {
    int t = blockIdx.x * 256 + threadIdx.x;
    int n = t >> 4, lane = t & 15;
    if (n >= NNODES) return;
    int k = n ? off[n - 1] : 0;
    int end = off[n];
    int fo = lane * 8;
    float a[8] = {0.f, 0.f, 0.f, 0.f, 0.f, 0.f, 0.f, 0.f};
    for (; k + 3 < end; k += 4) {
        uint2 e0 = epk[k], e1 = epk[k + 1], e2 = epk[k + 2], e3 = epk[k + 3];
        uint4 v0 = *(const uint4*)(hin + e0.x * HID + fo);
        uint4 v1 = *(const uint4*)(hin + e1.x * HID + fo);
        uint4 v2 = *(const uint4*)(hin + e2.x * HID + fo);
        uint4 v3 = *(const uint4*)(hin + e3.x * HID + fo);
        acc8(a, __uint_as_float(e0.y), v0);
        acc8(a, __uint_as_float(e1.y), v1);
        acc8(a, __uint_as_float(e2.y), v2);
        acc8(a, __uint_as_float(e3.y), v3);
    }
    for (; k < end; k++) {
        uint2 e = epk[k];
        uint4 v = *(const uint4*)(hin + e.x * HID + fo);
        acc8(a, __uint_as_float(e.y), v);
    }
    uint4 o;
    o.x = (unsigned)f2bf(a[0]) | ((unsigned)f2bf(a[1]) << 16);
    o.y = (unsigned)f2bf(a[2]) | ((unsigned)f2bf(a[3]) << 16);
    o.z = (unsigned)f2bf(a[4]) | ((unsigned)f2bf(a[5]) << 16);
    o.w = (unsigned)f2bf(a[6]) | ((unsigned)f2bf(a[7]) << 16);
    *(uint4*)(hout + n * HID + fo) = o;
}

// ---------------- layer-1 combine -> bf16 P0 ----------------
__global__ void combine1(const float* __restrict__ x, const float* __restrict__ h1,
                         const float* __restrict__ h2, const float* __restrict__ h3,
                         const float* __restrict__ W1, const float* __restrict__ b1,
                         ushort_t* __restrict__ P0) {
    __shared__ float hs[4][16];
    int n0 = blockIdx.x * 4;
    int j = threadIdx.x;  // 0..127
    if (j < 64) {
        int n = j >> 4, v = j & 15, k = v >> 2, i = v & 3;
        const float* src = (k == 0) ? x : (k == 1) ? h1 : (k == 2) ? h2 : h3;
        hs[n][v] = src[(n0 + n) * 4 + i];
    }
    __syncthreads();
    float w[16];
#pragma unroll
    for (int v = 0; v < 16; v++) w[v] = W1[v * 128 + j];
    float bb = b1[j];
#pragma unroll
    for (int n = 0; n < 4; n++) {
        float acc = bb;
#pragma unroll
        for (int v = 0; v < 16; v++) acc += hs[n][v] * w[v];
        P0[(n0 + n) * 128 + j] = f2bf(fmaxf(acc, 0.0f));
    }
}

// ---------------- fused MFMA + pool, B staged in LDS ----------------
__global__ __launch_bounds__(256) void gemm4p(
    const ushort_t* __restrict__ P0, const ushort_t* __restrict__ P1,
    const ushort_t* __restrict__ P2, const ushort_t* __restrict__ P3,
    const ushort_t* __restrict__ Wt, const float* __restrict__ b2,
    const int* __restrict__ batch, float* __restrict__ sums) {
    __shared__ ushort_t Bs[32768];   // 64 KB: 128 rows x 512 B (2 hops worth of K)
    int tid = threadIdx.x;
    int w = tid >> 6, lane = tid & 63;
    int r16 = lane & 15, kg = lane >> 4;
    int tb = blockIdx.x * 128 + w * 32;   // wave tile base node; 100000 % 32 == 0
    bool active = (tb < NNODES);
    floatx4 acc[2][8];
#pragma unroll
    for (int s = 0; s < 2; s++)
#pragma unroll
        for (int n = 0; n < 8; n++) acc[s][n] = (floatx4){0.f, 0.f, 0.f, 0.f};
    const ushort_t* Ps[4] = {P0, P1, P2, P3};
    for (int stage = 0; stage < 2; stage++) {
        __syncthreads();   // protect LDS reuse across stages
#pragma unroll
        for (int i = 0; i < 16; i++) {
            int idx = i * 256 + tid;          // 16B-unit index, 4096 total
            int r = idx >> 5;                 // row 0..127
            int slot = idx & 31;
            int cb = (slot * 16) ^ ((r & 7) << 4);
            *(uint4*)((char*)Bs + r * 512 + cb) =
                *(const uint4*)(Wt + r * 512 + stage * 256 + slot * 8);
        }
        __syncthreads();
        if (active) {
#pragma unroll
            for (int hh = 0; hh < 2; hh++) {
                const ushort_t* P = Ps[stage * 2 + hh];
#pragma unroll
                for (int k0 = 0; k0 < 128; k0 += 32) {
                    int f = k0 + kg * 8;
                    short8 a0 = *(const short8*)(P + (tb + r16) * HID + f);
                    short8 a1 = *(const short8*)(P + (tb + 16 + r16) * HID + f);
#pragma unroll
                    for (int n = 0; n < 8; n++) {
                        int r = n * 16 + r16;
                        int cb = (hh * 256 + k0 * 2 + kg * 16) ^ ((r & 7) << 4);
                        short8 b = *(const short8*)((const char*)Bs + r * 512 + cb);
                        acc[0][n] = __builtin_amdgcn_mfma_f32_16x16x32_bf16(a0, b, acc[0][n], 0, 0, 0);
                        acc[1][n] = __builtin_amdgcn_mfma_f32_16x16x32_bf16(a1, b, acc[1][n], 0, 0, 0);
                    }
                }
            }
        }
    }
    if (!active) return;
    float bb[8];
#pragma unroll
    for (int n = 0; n < 8; n++) bb[n] = b2[n * 16 + r16];
    int g0 = batch[tb], g31 = batch[tb + 31];
    if (g0 == g31) {
#pragma unroll
        for (int n = 0; n < 8; n++) {
            float s = 0.0f;
#pragma unroll
            for (int st = 0; st < 2; st++)
#pragma unroll
                for (int r = 0; r < 4; r++) s += fmaxf(acc[st][n][r] + bb[n], 0.0f);
            s += __shfl_xor(s, 16);
            s += __shfl_xor(s, 32);
            if (kg == 0) atomicAdd(&sums[g0 * HID + n * 16 + r16], s);
        }
    } else {
#pragma unroll
        for (int st = 0; st < 2; st++)
#pragma unroll
            for (int r = 0; r < 4; r++) {
                int g = batch[tb + st * 16 + kg * 4 + r];
#pragma unroll
                for (int n = 0; n < 8; n++)
                    atomicAdd(&sums[g * HID + n * 16 + r16], fmaxf(acc[st][n][r] + bb[n], 0.0f));
            }
    }
}

// ---------------- head ----------------
__global__ void head_kernel(const float* __restrict__ sums, const int* __restrict__ first,
                            const int* __restrict__ last,
                            const float* __restrict__ Wlin, const float* __restrict__ blin,
                            float* __restrict__ out) {
    int g = threadIdx.x;
    if (g >= NGRAPHS) return;
    float cnt = (float)(last[g] - first[g] + 1);
    if (cnt < 1.0f) cnt = 1.0f;
    float l0 = blin[0], l1 = blin[1];
    for (int i = 0; i < HID; i++) {
        float p = sums[g * HID + i] / cnt;
        l0 += p * Wlin[i * 2 + 0];
        l1 += p * Wlin[i * 2 + 1];
    }
    float m = fmaxf(l0, l1);
    float e0 = __expf(l0 - m), e1 = __expf(l1 - m);
    float s = e0 + e1;
    out[g * 2 + 0] = e0 / s;
    out[g * 2 + 1] = e1 / s;
}

// ---------------- workspace layout (4-byte units) ----------------
#define OFF_DINV  0
#define OFF_OFF   (OFF_DINV + NPAD)
// ---- single-memset region: sums, first, last, bcnt (contiguous) ----
#define OFF_SUMS  (OFF_OFF + NPAD)
#define OFF_FIRST (OFF_SUMS + NGRAPHS * HID)
#define OFF_LAST  (OFF_FIRST + NGRAPHS)
#define OFF_BCNT  (OFF_LAST + NGRAPHS)
#define ZERO_WORDS (NGRAPHS * HID + NGRAPHS + NGRAPHS + 800)
// ----
#define OFF_BBASE (OFF_BCNT + 800)
#define OFF_GC    (OFF_BBASE + 800)
#define OFF_ENT   (OFF_GC + 800)                  // uint[NEDGES]
#define OFF_SRC   (OFF_ENT + NEDGES)              // int[NEDGES]
#define OFF_EPK   (OFF_SRC + NEDGES)              // uint2[NEDGES] (8B aligned)
#define OFF_P0    (OFF_EPK + 2 * NEDGES)
#define OFF_P1    (OFF_P0 + NNODES * HID / 2)     // bf16 [N,128] = N*64 words
#define OFF_P2    (OFF_P1 + NNODES * HID / 2)
#define OFF_P3    (OFF_P2 + NNODES * HID / 2)
#define OFF_H1    (OFF_P3 + NNODES * HID / 2)
#define OFF_H2    (OFF_H1 + NNODES * 4)
#define OFF_H3    (OFF_H2 + NNODES * 4)
#define OFF_WT    (OFF_H3 + NNODES * 4)

extern "C" void kernel_launch(void* const* d_in, const int* in_sizes, int n_in,
                              void* d_out, int out_size, void* d_ws, size_t ws_size,
                              hipStream_t stream) {
    const float* x    = (const float*)d_in[0];
    const float* W1   = (const float*)d_in[1];
    const float* b1   = (const float*)d_in[2];
    const float* W2   = (const float*)d_in[3];
    const float* b2   = (const float*)d_in[4];
    const float* Wlin = (const float*)d_in[5];
    const float* blin = (const float*)d_in[6];
    const int* ei     = (const int*)d_in[7];
    const int* batch  = (const int*)d_in[8];
    float* out = (float*)d_out;

    const int* row = ei;
    const int* col = ei + NEDGES;

    float* ws = (float*)d_ws;
    float* dinv    = ws + OFF_DINV;
    int*   off     = (int*)(ws + OFF_OFF);
    float* sums    = ws + OFF_SUMS;
    int*   first   = (int*)(ws + OFF_FIRST);
    int*   last    = (int*)(ws + OFF_LAST);
    int*   bcnt    = (int*)(ws + OFF_BCNT);
    int*   bbase   = (int*)(ws + OFF_BBASE);
    int*   gc      = (int*)(ws + OFF_GC);
    uint_t* ent    = (uint_t*)(ws + OFF_ENT);
    int*   csr_src = (int*)(ws + OFF_SRC);
    uint2* epk     = (uint2*)(ws + OFF_EPK);
    ushort_t* P0   = (ushort_t*)(ws + OFF_P0);
    ushort_t* P1   = (ushort_t*)(ws + OFF_P1);
    ushort_t* P2   = (ushort_t*)(ws + OFF_P2);
    ushort_t* P3   = (ushort_t*)(ws + OFF_P3);
    float* h1      = ws + OFF_H1;
    float* h2      = ws + OFF_H2;
    float* h3      = ws + OFF_H3;
    ushort_t* Wt   = (ushort_t*)(ws + OFF_WT);

    // ---- init (single memset: sums + first + last + bcnt) ----
    hipMemsetAsync(sums, 0, ZERO_WORDS * sizeof(float), stream);

    // ---- CSR build (bucket counting sort; sortb also emits dinv) ----
    hist_k<<<NCHB, 256, 0, stream>>>(col, bcnt);
    bscan_k<<<1, 1024, 0, stream>>>(bcnt, bbase, gc);
    bfill_k<<<NCHB, 256, 0, stream>>>(row, col, gc, ent);
    sortb_k<<<NBKT, 256, 0, stream>>>(ent, bbase, csr_src, dinv, off);
    misc_k<<<NPAD / 256, 256, 0, stream>>>(W2, Wt, batch, first, last);

    // ---- layer 1 (fp32, F=4); hop 1 also emits packed edges epk ----
    gprop4w<<<NPAD / 256, 256, 0, stream>>>(off, csr_src, dinv, x, h1, epk);
    gprop4<<<NPAD / 256, 256, 0, stream>>>(off, epk, h1, h2);
    gprop4<<<NPAD / 256, 256, 0, stream>>>(off, epk, h2, h3);
    combine1<<<NNODES / 4, 128, 0, stream>>>(x, h1, h2, h3, W1, b1, P0);

    // ---- layer 2 hops (bf16) ----
    gprop128<<<NPAD * 16 / 256, 256, 0, stream>>>(off, epk, P0, P1);
    gprop128<<<NPAD * 16 / 256, 256, 0, stream>>>(off, epk, P1, P2);
    gprop128<<<NPAD * 16 / 256, 256, 0, stream>>>(off, epk, P2, P3);

    // ---- fused MFMA combine + pool (K=512, B in LDS) ----
    gemm4p<<<(NNODES + 127) / 128, 256, 0, stream>>>(P0, P1, P2, P3, Wt, b2, batch, sums);

    // ---- head ----
    head_kernel<<<1, 128, 0, stream>>>(sums, first, last, Wlin, blin, out);
}

// Round 14
// 359.019 us; speedup vs baseline: 2.1348x; 1.0132x over previous
//
#include <hip/hip_runtime.h>

#define NNODES 100000
#define NEDGES 1600000
#define NGRAPHS 128
#define HID 128
#define NBKT 782            // ceil(100000/128)
#define NPAD  (NBKT * 128)  // 100096
#define CHUNK 8192
#define NCHB ((NEDGES + CHUNK - 1) / CHUNK)   // 196
#define MAXB 3072           // bucket edge cap (mean 2048, sigma ~45)
#define HTHREADS (NCHB * 256)                 // 50176

typedef unsigned short ushort_t;
typedef unsigned int uint_t;
typedef __attribute__((ext_vector_type(8))) short short8;
typedef __attribute__((ext_vector_type(4))) float floatx4;

__device__ __forceinline__ float bf2f(ushort_t u) {
    return __uint_as_float(((unsigned)u) << 16);
}
__device__ __forceinline__ ushort_t f2bf(float f) {
    unsigned u = __float_as_uint(f);
    return (ushort_t)((u + 0x7fffu + ((u >> 16) & 1u)) >> 16);
}

// ---------------- bucket histogram (LDS-staged) + fused Wt transpose / bounds ----------------
__global__ void hist_k(const int* __restrict__ col, int* __restrict__ bcnt,
                       const float* __restrict__ W2, ushort_t* __restrict__ Wt,
                       const int* __restrict__ batch,
                       int* __restrict__ first, int* __restrict__ last) {
    __shared__ int l[NBKT];
    for (int i = threadIdx.x; i < NBKT; i += 256) l[i] = 0;
    __syncthreads();
    int base = blockIdx.x * CHUNK;
    int lim = base + CHUNK < NEDGES ? base + CHUNK : NEDGES;
    for (int e = base + threadIdx.x; e < lim; e += 256)
        atomicAdd(&l[col[e] >> 7], 1);
    __syncthreads();
    for (int i = threadIdx.x; i < NBKT; i += 256)
        if (l[i]) atomicAdd(&bcnt[i], l[i]);
    // fused misc work, strided over the whole grid
    int gtid = blockIdx.x * 256 + threadIdx.x;
    for (int i = gtid; i < 512 * 128; i += HTHREADS) {
        int j = i >> 9, k = i & 511;
        Wt[i] = f2bf(W2[k * 128 + j]);   // Wt[j][k], k = hop*128+i
    }
    for (int i = gtid; i < NNODES; i += HTHREADS) {
        int g = batch[i];
        if (i == 0 || batch[i - 1] != g) first[g] = i;
        if (i == NNODES - 1 || batch[i + 1] != g) last[g] = i;
    }
}

// ---------------- scan 782 buckets (single block) ----------------
__global__ void bscan_k(const int* __restrict__ bcnt, int* __restrict__ bbase,
                        int* __restrict__ gc) {
    __shared__ int l[1024];
    int t = threadIdx.x;
    int v0 = (t < NBKT) ? bcnt[t] : 0;
    l[t] = v0;
    __syncthreads();
    for (int d = 1; d < 1024; d <<= 1) {
        int v = (t >= d) ? l[t - d] : 0;
        __syncthreads();
        l[t] += v;
        __syncthreads();
    }
    if (t < NBKT) { int ex = l[t] - v0; bbase[t] = ex; gc[t] = ex; }
    if (t == 0) bbase[NBKT] = NEDGES;
}

// ---------------- bucket scatter: one range-claim atomic per (block,bucket) ----------------
__global__ void bfill_k(const int* __restrict__ row, const int* __restrict__ col,
                        int* __restrict__ gc, uint_t* __restrict__ entry) {
    __shared__ int lcnt[NBKT], lbase[NBKT];
    for (int i = threadIdx.x; i < NBKT; i += 256) lcnt[i] = 0;
    __syncthreads();
    int base = blockIdx.x * CHUNK;
    int lim = base + CHUNK < NEDGES ? base + CHUNK : NEDGES;
    for (int e = base + threadIdx.x; e < lim; e += 256)
        atomicAdd(&lcnt[col[e] >> 7], 1);
    __syncthreads();
    for (int i = threadIdx.x; i < NBKT; i += 256) {
        int c = lcnt[i];
        lbase[i] = c ? atomicAdd(&gc[i], c) : 0;
        lcnt[i] = 0;   // reuse as fill cursor
    }
    __syncthreads();
    for (int e = base + threadIdx.x; e < lim; e += 256) {
        int c = col[e];
        int b = c >> 7;
        int pos = lbase[b] + atomicAdd(&lcnt[b], 1);
        entry[pos] = (uint_t)row[e] | ((uint_t)(c & 127) << 17);
    }
}

// ---------------- per-bucket LDS counting sort -> csr_src, dinv, off ----------------
__global__ void sortb_k(const uint_t* __restrict__ entry, const int* __restrict__ bbase,
                        int* __restrict__ csr_src, float* __restrict__ dinv,
                        int* __restrict__ off) {
    __shared__ uint_t ents[MAXB];
    __shared__ uint_t sorted[MAXB];
    __shared__ int ncnt[128], nsc[128], nfill[128];
    int b = blockIdx.x;
    int base = bbase[b];
    int cnt = bbase[b + 1] - base;
    if (cnt > MAXB) cnt = MAXB;
    int t = threadIdx.x;
    if (t < 128) { ncnt[t] = 0; nfill[t] = 0; }
    __syncthreads();
    for (int i = t; i < cnt; i += 256) {
        uint_t v = entry[base + i];
        ents[i] = v;
        atomicAdd(&ncnt[v >> 17], 1);
    }
    __syncthreads();
    if (t < 128) nsc[t] = ncnt[t];
    __syncthreads();
    for (int d = 1; d < 128; d <<= 1) {
        int v = (t >= d && t < 128) ? nsc[t - d] : 0;
        __syncthreads();
        if (t < 128) nsc[t] += v;   // inclusive scan
        __syncthreads();
    }
    if (t < 128) {
        int n = b * 128 + t;
        if (n < NNODES) {
            off[n] = base + nsc[t];
            dinv[n] = (ncnt[t] > 0) ? rsqrtf((float)ncnt[t]) : 0.0f;
        }
        nsc[t] -= ncnt[t];          // exclusive
    }
    __syncthreads();
    for (int i = t; i < cnt; i += 256) {
        uint_t v = ents[i];
        int dl = v >> 17;
        int pos = nsc[dl] + atomicAdd(&nfill[dl], 1);
        sorted[pos] = v & 0x1FFFFu;
    }
    __syncthreads();
    for (int i = t; i < cnt; i += 256) csr_src[base + i] = (int)sorted[i];
}

// ---------------- layer-1 hop 1 (x -> h1) + emit packed edges epk ----------------
__global__ void gprop4w(const int* __restrict__ off, const int* __restrict__ csr_src,
                        const float* __restrict__ dinv,
                        const float* __restrict__ hin, float* __restrict__ hout,
                        uint2* __restrict__ epk) {
    int n = blockIdx.x * 256 + threadIdx.x;
    if (n >= NNODES) return;
    int k = n ? off[n - 1] : 0;
    int end = off[n];
    float dn = dinv[n];
    float4 acc = {0.f, 0.f, 0.f, 0.f};
    for (; k + 1 < end; k += 2) {
        int s0 = csr_src[k], s1 = csr_src[k + 1];
        float w0 = dinv[s0] * dn, w1 = dinv[s1] * dn;
        epk[k]     = make_uint2((uint_t)s0, __float_as_uint(w0));
        epk[k + 1] = make_uint2((uint_t)s1, __float_as_uint(w1));
        float4 v0 = *(const float4*)(hin + s0 * 4);
        float4 v1 = *(const float4*)(hin + s1 * 4);
        acc.x += w0 * v0.x + w1 * v1.x;
        acc.y += w0 * v0.y + w1 * v1.y;
        acc.z += w0 * v0.z + w1 * v1.z;
        acc.w += w0 * v0.w + w1 * v1.w;
    }
    if (k < end) {
        int s = csr_src[k];
        float w = dinv[s] * dn;
        epk[k] = make_uint2((uint_t)s, __float_as_uint(w));
        float4 v = *(const float4*)(hin + s * 4);
        acc.x += w * v.x; acc.y += w * v.y; acc.z += w * v.z; acc.w += w * v.w;
    }
    *(float4*)(hout + n * 4) = acc;
}

// ---------------- layer-1 gather (F=4, fp32), packed edges, unroll 8 ----------------
__global__ void gprop4(const int* __restrict__ off, const uint2* __restrict__ epk,
                       const float* __restrict__ hin, float* __restrict__ hout) {
    int n = blockIdx.x * 256 + threadIdx.x;
    if (n >= NNODES) return;
    int k = n ? off[n - 1] : 0;
    int end = off[n];
    float4 acc = {0.f, 0.f, 0.f, 0.f};
    for (; k + 7 < end; k += 8) {
        uint2 e0 = epk[k],     e1 = epk[k + 1], e2 = epk[k + 2], e3 = epk[k + 3];
        uint2 e4 = epk[k + 4], e5 = epk[k + 5], e6 = epk[k + 6], e7 = epk[k + 7];
        float4 v0 = *(const float4*)(hin + e0.x * 4);
        float4 v1 = *(const float4*)(hin + e1.x * 4);
        float4 v2 = *(const float4*)(hin + e2.x * 4);
        float4 v3 = *(const float4*)(hin + e3.x * 4);
        float4 v4 = *(const float4*)(hin + e4.x * 4);
        float4 v5 = *(const float4*)(hin + e5.x * 4);
        float4 v6 = *(const float4*)(hin + e6.x * 4);
        float4 v7 = *(const float4*)(hin + e7.x * 4);
        float w0 = __uint_as_float(e0.y), w1 = __uint_as_float(e1.y);
        float w2 = __uint_as_float(e2.y), w3 = __uint_as_float(e3.y);
        float w4 = __uint_as_float(e4.y), w5 = __uint_as_float(e5.y);
        float w6 = __uint_as_float(e6.y), w7 = __uint_as_float(e7.y);
        acc.x += w0 * v0.x + w1 * v1.x + w2 * v2.x + w3 * v3.x
               + w4 * v4.x + w5 * v5.x + w6 * v6.x + w7 * v7.x;
        acc.y += w0 * v0.y + w1 * v1.y + w2 * v2.y + w3 * v3.y
               + w4 * v4.y + w5 * v5.y + w6 * v6.y + w7 * v7.y;
        acc.z += w0 * v0.z + w1 * v1.z + w2 * v2.z + w3 * v3.z
               + w4 * v4.z + w5 * v5.z + w6 * v6.z + w7 * v7.z;
        acc.w += w0 * v0.w + w1 * v1.w + w2 * v2.w + w3 * v3.w
               + w4 * v4.w + w5 * v5.w + w6 * v6.w + w7 * v7.w;
    }
    for (; k + 3 < end; k += 4) {
        uint2 e0 = epk[k], e1 = epk[k + 1], e2 = epk[k + 2], e3 = epk[k + 3];
        float w0 = __uint_as_float(e0.y), w1 = __uint_as_float(e1.y);
        float w2 = __uint_as_float(e2.y), w3 = __uint_as_float(e3.y);
        float4 v0 = *(const float4*)(hin + e0.x * 4);
        float4 v1 = *(const float4*)(hin + e1.x * 4);
        float4 v2 = *(const float4*)(hin + e2.x * 4);
        float4 v3 = *(const float4*)(hin + e3.x * 4);
        acc.x += w0 * v0.x + w1 * v1.x + w2 * v2.x + w3 * v3.x;
        acc.y += w0 * v0.y + w1 * v1.y + w2 * v2.y + w3 * v3.y;
        acc.z += w0 * v0.z + w1 * v1.z + w2 * v2.z + w3 * v3.z;
        acc.w += w0 * v0.w + w1 * v1.w + w2 * v2.w + w3 * v3.w;
    }
    for (; k < end; k++) {
        uint2 e = epk[k];
        float w = __uint_as_float(e.y);
        float4 v = *(const float4*)(hin + e.x * 4);
        acc.x += w * v.x; acc.y += w * v.y; acc.z += w * v.z; acc.w += w * v.w;
    }
    *(float4*)(hout + n * 4) = acc;
}

// ---------------- layer-2 gather helper: acc8 += wgt * bf16x8(v) ----------------
__device__ __forceinline__ void acc8(float* a, float wgt, uint4 v) {
    a[0] += wgt * __uint_as_float(v.x << 16);
    a[1] += wgt * __uint_as_float(v.x & 0xffff0000u);
    a[2] += wgt * __uint_as_float(v.y << 16);
    a[3] += wgt * __uint_as_float(v.y & 0xffff0000u);
    a[4] += wgt * __uint_as_float(v.z << 16);
    a[5] += wgt * __uint_as_float(v.z & 0xffff0000u);
    a[6] += wgt * __uint_as_float(v.w << 16);
    a[7] += wgt * __uint_as_float(v.w & 0xffff0000u);
}

// ---------------- layer-2 gather (F=128 bf16), 16 lanes/node, unroll 4 (floor config) ----------------
__global__ void gprop128(const int* __restrict__ off, const uint2* __restrict__ epk,
                         const ushort_t* __restrict__ hin, ushort_t* __restrict__ hout) {
    int t = blockIdx.x * 256 + threadIdx.x;
    int n = t >> 4, lane = t & 15;
    if (n >= NNODES) return;
    int k = n ? off[n - 1] : 0;
    int end = off[n];
    int fo = lane * 8;
    float a[8] = {0.f, 0.f, 0.f, 0.f, 0.f, 0.f, 0.f, 0.f};
    for (; k + 3 < end; k += 4) {
        uint2 e0 = epk[k], e1 = epk[k + 1], e2 = epk[k + 2], e3 = epk[k + 3];
        uint4 v0 = *(const uint4*)(hin + e0.x * HID + fo);
        uint4 v1 = *(const uint4*)(hin + e1.x * HID + fo);
        uint4 v2 = *(const uint4*)(hin + e2.x * HID + fo);
        uint4 v3 = *(const uint4*)(hin + e3.x * HID + fo);
        acc8(a, __uint_as_float(e0.y), v0);
        acc8(a, __uint_as_float(e1.y), v1);
        acc8(a, __uint_as_float(e2.y), v2);
        acc8(a, __uint_as_float(e3.y), v3);
    }
    for (; k < end; k++) {
        uint2 e = epk[k];
        uint4 v = *(const uint4*)(hin + e.x * HID + fo);
        acc8(a, __uint_as_float(e.y), v);
    }
    uint4 o;
    o.x = (unsigned)f2bf(a[0]) | ((unsigned)f2bf(a[1]) << 16);
    o.y = (unsigned)f2bf(a[2]) | ((unsigned)f2bf(a[3]) << 16);
    o.z = (unsigned)f2bf(a[4]) | ((unsigned)f2bf(a[5]) << 16);
    o.w = (unsigned)f2bf(a[6]) | ((unsigned)f2bf(a[7]) << 16);
    *(uint4*)(hout + n * HID + fo) = o;
}

// ---------------- layer-1 combine -> bf16 P0 ----------------
__global__ void combine1(const float* __restrict__ x, const float* __restrict__ h1,
                         const float* __restrict__ h2, const float* __restrict__ h3,
                         const float* __restrict__ W1, const float* __restrict__ b1,
                         ushort_t* __restrict__ P0) {
    __shared__ float hs[4][16];
    int n0 = blockIdx.x * 4;
    int j = threadIdx.x;  // 0..127
    if (j < 64) {
        int n = j >> 4, v = j & 15, k = v >> 2, i = v & 3;
        const float* src = (k == 0) ? x : (k == 1) ? h1 : (k == 2) ? h2 : h3;
        hs[n][v] = src[(n0 + n) * 4 + i];
    }
    __syncthreads();
    float w[16];
#pragma unroll
    for (int v = 0; v < 16; v++) w[v] = W1[v * 128 + j];
    float bb = b1[j];
#pragma unroll
    for (int n = 0; n < 4; n++) {
        float acc = bb;
#pragma unroll
        for (int v = 0; v < 16; v++) acc += hs[n][v] * w[v];
        P0[(n0 + n) * 128 + j] = f2bf(fmaxf(acc, 0.0f));
    }
}

// ---------------- fused MFMA + pool, B staged in LDS ----------------
__global__ __launch_bounds__(256) void gemm4p(
    const ushort_t* __restrict__ P0, const ushort_t* __restrict__ P1,
    const ushort_t* __restrict__ P2, const ushort_t* __restrict__ P3,
    const ushort_t* __restrict__ Wt, const float* __restrict__ b2,
    const int* __restrict__ batch, float* __restrict__ sums) {
    __shared__ ushort_t Bs[32768];   // 64 KB: 128 rows x 512 B (2 hops worth of K)
    int tid = threadIdx.x;
    int w = tid >> 6, lane = tid & 63;
    int r16 = lane & 15, kg = lane >> 4;
    int tb = blockIdx.x * 128 + w * 32;   // wave tile base node; 100000 % 32 == 0
    bool active = (tb < NNODES);
    floatx4 acc[2][8];
#pragma unroll
    for (int s = 0; s < 2; s++)
#pragma unroll
        for (int n = 0; n < 8; n++) acc[s][n] = (floatx4){0.f, 0.f, 0.f, 0.f};
    const ushort_t* Ps[4] = {P0, P1, P2, P3};
    for (int stage = 0; stage < 2; stage++) {
        __syncthreads();   // protect LDS reuse across stages
#pragma unroll
        for (int i = 0; i < 16; i++) {
            int idx = i * 256 + tid;          // 16B-unit index, 4096 total
            int r = idx >> 5;                 // row 0..127
            int slot = idx & 31;
            int cb = (slot * 16) ^ ((r & 7) << 4);
            *(uint4*)((char*)Bs + r * 512 + cb) =
                *(const uint4*)(Wt + r * 512 + stage * 256 + slot * 8);
        }
        __syncthreads();
        if (active) {
#pragma unroll
            for (int hh = 0; hh < 2; hh++) {
                const ushort_t* P = Ps[stage * 2 + hh];
#pragma unroll
                for (int k0 = 0; k0 < 128; k0 += 32) {
                    int f = k0 + kg * 8;
                    short8 a0 = *(const short8*)(P + (tb + r16) * HID + f);
                    short8 a1 = *(const short8*)(P + (tb + 16 + r16) * HID + f);
#pragma unroll
                    for (int n = 0; n < 8; n++) {
                        int r = n * 16 + r16;
                        int cb = (hh * 256 + k0 * 2 + kg * 16) ^ ((r & 7) << 4);
                        short8 b = *(const short8*)((const char*)Bs + r * 512 + cb);
                        acc[0][n] = __builtin_amdgcn_mfma_f32_16x16x32_bf16(a0, b, acc[0][n], 0, 0, 0);
                        acc[1][n] = __builtin_amdgcn_mfma_f32_16x16x32_bf16(a1, b, acc[1][n], 0, 0, 0);
                    }
                }
            }
        }
    }
    if (!active) return;
    float bb[8];
#pragma unroll
    for (int n = 0; n < 8; n++) bb[n] = b2[n * 16 + r16];
    int g0 = batch[tb], g31 = batch[tb + 31];
    if (g0 == g31) {
#pragma unroll
        for (int n = 0; n < 8; n++) {
            float s = 0.0f;
#pragma unroll
            for (int st = 0; st < 2; st++)
#pragma unroll
                for (int r = 0; r < 4; r++) s += fmaxf(acc[st][n][r] + bb[n], 0.0f);
            s += __shfl_xor(s, 16);
            s += __shfl_xor(s, 32);
            if (kg == 0) atomicAdd(&sums[g0 * HID + n * 16 + r16], s);
        }
    } else {
#pragma unroll
        for (int st = 0; st < 2; st++)
#pragma unroll
            for (int r = 0; r < 4; r++) {
                int g = batch[tb + st * 16 + kg * 4 + r];
#pragma unroll
                for (int n = 0; n < 8; n++)
                    atomicAdd(&sums[g * HID + n * 16 + r16], fmaxf(acc[st][n][r] + bb[n], 0.0f));
            }
    }
}

// ---------------- head ----------------
__global__ void head_kernel(const float* __restrict__ sums, const int* __restrict__ first,
                            const int* __restrict__ last,
                            const float* __restrict__ Wlin, const float* __restrict__ blin,
                            float* __restrict__ out) {
    int g = threadIdx.x;
    if (g >= NGRAPHS) return;
    float cnt = (float)(last[g] - first[g] + 1);
    if (cnt < 1.0f) cnt = 1.0f;
    float l0 = blin[0], l1 = blin[1];
    for (int i = 0; i < HID; i++) {
        float p = sums[g * HID + i] / cnt;
        l0 += p * Wlin[i * 2 + 0];
        l1 += p * Wlin[i * 2 + 1];
    }
    float m = fmaxf(l0, l1);
    float e0 = __expf(l0 - m), e1 = __expf(l1 - m);
    float s = e0 + e1;
    out[g * 2 + 0] = e0 / s;
    out[g * 2 + 1] = e1 / s;
}

// ---------------- workspace layout (4-byte units) ----------------
#define OFF_DINV  0
#define OFF_OFF   (OFF_DINV + NPAD)
// ---- single-memset region: sums, first, last, bcnt (contiguous) ----
#define OFF_SUMS  (OFF_OFF + NPAD)
#define OFF_FIRST (OFF_SUMS + NGRAPHS * HID)
#define OFF_LAST  (OFF_FIRST + NGRAPHS)
#define OFF_BCNT  (OFF_LAST + NGRAPHS)
#define ZERO_WORDS (NGRAPHS * HID + NGRAPHS + NGRAPHS + 800)
// ----
#define OFF_BBASE (OFF_BCNT + 800)
#define OFF_GC    (OFF_BBASE + 800)
#define OFF_ENT   (OFF_GC + 800)                  // uint[NEDGES]
#define OFF_SRC   (OFF_ENT + NEDGES)              // int[NEDGES]
#define OFF_EPK   (OFF_SRC + NEDGES)              // uint2[NEDGES] (8B aligned)
#define OFF_P0    (OFF_EPK + 2 * NEDGES)
#define OFF_P1    (OFF_P0 + NNODES * HID / 2)     // bf16 [N,128] = N*64 words
#define OFF_P2    (OFF_P1 + NNODES * HID / 2)
#define OFF_P3    (OFF_P2 + NNODES * HID / 2)
#define OFF_H1    (OFF_P3 + NNODES * HID / 2)
#define OFF_H2    (OFF_H1 + NNODES * 4)
#define OFF_H3    (OFF_H2 + NNODES * 4)
#define OFF_WT    (OFF_H3 + NNODES * 4)

extern "C" void kernel_launch(void* const* d_in, const int* in_sizes, int n_in,
                              void* d_out, int out_size, void* d_ws, size_t ws_size,
                              hipStream_t stream) {
    const float* x    = (const float*)d_in[0];
    const float* W1   = (const float*)d_in[1];
    const float* b1   = (const float*)d_in[2];
    const float* W2   = (const float*)d_in[3];
    const float* b2   = (const float*)d_in[4];
    const float* Wlin = (const float*)d_in[5];
    const float* blin = (const float*)d_in[6];
    const int* ei     = (const int*)d_in[7];
    const int* batch  = (const int*)d_in[8];
    float* out = (float*)d_out;

    const int* row = ei;
    const int* col = ei + NEDGES;

    float* ws = (float*)d_ws;
    float* dinv    = ws + OFF_DINV;
    int*   off     = (int*)(ws + OFF_OFF);
    float* sums    = ws + OFF_SUMS;
    int*   first   = (int*)(ws + OFF_FIRST);
    int*   last    = (int*)(ws + OFF_LAST);
    int*   bcnt    = (int*)(ws + OFF_BCNT);
    int*   bbase   = (int*)(ws + OFF_BBASE);
    int*   gc      = (int*)(ws + OFF_GC);
    uint_t* ent    = (uint_t*)(ws + OFF_ENT);
    int*   csr_src = (int*)(ws + OFF_SRC);
    uint2* epk     = (uint2*)(ws + OFF_EPK);
    ushort_t* P0   = (ushort_t*)(ws + OFF_P0);
    ushort_t* P1   = (ushort_t*)(ws + OFF_P1);
    ushort_t* P2   = (ushort_t*)(ws + OFF_P2);
    ushort_t* P3   = (ushort_t*)(ws + OFF_P3);
    float* h1      = ws + OFF_H1;
    float* h2      = ws + OFF_H2;
    float* h3      = ws + OFF_H3;
    ushort_t* Wt   = (ushort_t*)(ws + OFF_WT);

    // ---- init (single memset: sums + first + last + bcnt) ----
    hipMemsetAsync(sums, 0, ZERO_WORDS * sizeof(float), stream);

    // ---- CSR build (bucket counting sort; sortb emits dinv; hist fused with Wt/bounds) ----
    hist_k<<<NCHB, 256, 0, stream>>>(col, bcnt, W2, Wt, batch, first, last);
    bscan_k<<<1, 1024, 0, stream>>>(bcnt, bbase, gc);
    bfill_k<<<NCHB, 256, 0, stream>>>(row, col, gc, ent);
    sortb_k<<<NBKT, 256, 0, stream>>>(ent, bbase, csr_src, dinv, off);

    // ---- layer 1 (fp32, F=4); hop 1 also emits packed edges epk ----
    gprop4w<<<NPAD / 256, 256, 0, stream>>>(off, csr_src, dinv, x, h1, epk);
    gprop4<<<NPAD / 256, 256, 0, stream>>>(off, epk, h1, h2);
    gprop4<<<NPAD / 256, 256, 0, stream>>>(off, epk, h2, h3);
    combine1<<<NNODES / 4, 128, 0, stream>>>(x, h1, h2, h3, W1, b1, P0);

    // ---- layer 2 hops (bf16) ----
    gprop128<<<NPAD * 16 / 256, 256, 0, stream>>>(off, epk, P0, P1);
    gprop128<<<NPAD * 16 / 256, 256, 0, stream>>>(off, epk, P1, P2);
    gprop128<<<NPAD * 16 / 256, 256, 0, stream>>>(off, epk, P2, P3);

    // ---- fused MFMA combine + pool (K=512, B in LDS) ----
    gemm4p<<<(NNODES + 127) / 128, 256, 0, stream>>>(P0, P1, P2, P3, Wt, b2, batch, sums);

    // ---- head ----
    head_kernel<<<1, 128, 0, stream>>>(sums, first, last, Wlin, blin, out);
}